// Round 13
// baseline (286.133 us; speedup 1.0000x reference)
//
#include <hip/hip_runtime.h>
#include <hip/hip_bf16.h>

typedef unsigned short ushort;
typedef unsigned long long u64;
typedef short bf16x8 __attribute__((ext_vector_type(8)));
typedef float f32x4 __attribute__((ext_vector_type(4)));

#define NB 8
#define SS 2048
#define DD 768
#define DKV 214
#define DKP 224
#define WROWS 256
#define MSHIFT 40.0f

__device__ __forceinline__ float bf2f(ushort u) {
  union { unsigned int i; float f; } v; v.i = ((unsigned int)u) << 16; return v.f;
}
__device__ __forceinline__ ushort f2bf(float f) {
  union { float f; unsigned int i; } v; v.f = f;
  unsigned int x = v.i;
  return (ushort)((x + 0x7fffu + ((x >> 16) & 1u)) >> 16);
}
__device__ __forceinline__ void split8v(f32x4 a, f32x4 b, bf16x8& h, bf16x8& l) {
#pragma unroll
  for (int j = 0; j < 4; ++j) {
    ushort h0 = f2bf(a[j]); h[j]     = (short)h0; l[j]     = (short)f2bf(a[j] - bf2f(h0));
    ushort h1 = f2bf(b[j]); h[j + 4] = (short)h1; l[j + 4] = (short)f2bf(b[j] - bf2f(h1));
  }
}
__device__ __forceinline__ bf16x8 cvt8v(f32x4 a, f32x4 b) {
  bf16x8 r;
#pragma unroll
  for (int j = 0; j < 4; ++j) { r[j] = (short)f2bf(a[j]); r[j + 4] = (short)f2bf(b[j]); }
  return r;
}
// async global->LDS, 16B per lane; LDS dest is wave-uniform base + lane*16
__device__ __forceinline__ void gload16(const void* g, void* l) {
  __builtin_amdgcn_global_load_lds(
      (const __attribute__((address_space(1))) void*)g,
      (__attribute__((address_space(3))) void*)l, 16, 0, 0);
}

// ---- stream prep: dmask -> 1 bit/elem (4.2 MB), rcp(isc) -> f16 (8.4 MB), Z zero ----
__global__ __launch_bounds__(256)
void prep_sm(const float* __restrict__ isc, const float* __restrict__ dmk,
             ushort* __restrict__ riscp, u64* __restrict__ dbits,
             float* __restrict__ Z)
{
  const int tid0 = blockIdx.x * 256 + threadIdx.x;
  const int stride = gridDim.x * 256;
  for (int i = tid0; i < NB * SS; i += stride) Z[i] = 0.f;
  for (int i = tid0; i < SS * SS; i += stride) {
    union { _Float16 h; ushort u; } cv;
    cv.h = (_Float16)__builtin_amdgcn_rcpf(isc[i]);
    riscp[i] = cv.u;
  }
  for (size_t i = tid0; i < (size_t)NB * SS * SS; i += stride) {
    u64 m = __ballot(dmk[i] > 0.5f);
    if ((threadIdx.x & 63) == 0) dbits[i >> 6] = m;
  }
}

// ---- weight prep. Wq,Wk -> k-packed [24][256][32] hi/lo; Wv -> [24][768][32] ----
__global__ __launch_bounds__(256)
void prep_w(const float* __restrict__ Wq, const float* __restrict__ Wk,
            const float* __restrict__ Wv,
            ushort* __restrict__ Wqh, ushort* __restrict__ Wql,
            ushort* __restrict__ Wkh, ushort* __restrict__ Wkl,
            ushort* __restrict__ Wvb)
{
  const int NW = WROWS * DD;
  const int NV = DD * DD;
  for (int i = blockIdx.x * 256 + threadIdx.x; i < 2 * NW + NV; i += gridDim.x * 256) {
    if (i < NW) {
      int r = i / DD, c = i % DD;
      float v = (r < DKV) ? Wq[i] : 0.f;
      ushort h = f2bf(v);
      int d = (c >> 5) * (WROWS * 32) + r * 32 + (c & 31);
      Wqh[d] = h; Wql[d] = f2bf(v - bf2f(h));
    } else if (i < 2 * NW) {
      int j = i - NW;
      int r = j / DD, c = j % DD;
      float v = (r < DKV) ? Wk[j] : 0.f;
      ushort h = f2bf(v);
      int d = (c >> 5) * (WROWS * 32) + r * 32 + (c & 31);
      Wkh[d] = h; Wkl[d] = f2bf(v - bf2f(h));
    } else {
      int j = i - 2 * NW;
      int r = j / DD, c = j % DD;
      Wvb[(c >> 5) * (DD * 32) + r * 32 + (c & 31)] = f2bf(Wv[j]);
    }
  }
}

// ---- fused Q+K projection -> k-packed hi/lo [b][7][2048][32] (unchanged R11) ----
__global__ __launch_bounds__(256, 4)
void gemm_qk(const float* __restrict__ x1, const float* __restrict__ x2,
             const ushort* __restrict__ Wqh, const ushort* __restrict__ Wql,
             const ushort* __restrict__ Wkh, const ushort* __restrict__ Wkl,
             const float* __restrict__ bq, const float* __restrict__ bk,
             ushort* __restrict__ Qph, ushort* __restrict__ Qpl,
             ushort* __restrict__ Kph, ushort* __restrict__ Kpl)
{
  const int m0 = blockIdx.x * 64;
  const int which = blockIdx.y >> 1;
  const int n0 = (blockIdx.y & 1) * 128;
  const int tid = threadIdx.x;
  const int w  = tid >> 6;
  const int l  = tid & 63;
  const int lr = l & 15;
  const int lh = l >> 4;

  const float*  A    = which ? x2 : x1;
  const ushort* Bh   = which ? Wkh : Wqh;
  const ushort* Bl   = which ? Wkl : Wql;
  const float*  bias = which ? bk : bq;
  ushort* Ch = which ? Kph : Qph;
  ushort* Cl = which ? Kpl : Qpl;

  __shared__ __align__(16) char lds[2][2][128][64];

  const int srow = (w << 4) + (l >> 2);
  const size_t gc = (size_t)srow * 64 + (size_t)((((l & 3) ^ ((srow >> 1) & 3))) << 4);
  const char* gbh = (const char*)Bh + (size_t)n0 * 64;
  const char* gbl = (const char*)Bl + (size_t)n0 * 64;

  const f32x4 fzero = {0.f, 0.f, 0.f, 0.f};
  f32x4 acc[8];
#pragma unroll
  for (int nt = 0; nt < 8; ++nt) acc[nt] = fzero;

  const float* arow = A + (size_t)(m0 + w * 16 + lr) * DD + lh * 8;

#define QKSTAGE(buf, kk) do {                                             \
    size_t ko = (size_t)(kk) * (WROWS * 64);                              \
    gload16(gbh + ko + gc,        &lds[buf][0][w << 4][0]);               \
    gload16(gbh + ko + gc + 4096, &lds[buf][0][(w << 4) + 64][0]);        \
    gload16(gbl + ko + gc,        &lds[buf][1][w << 4][0]);               \
    gload16(gbl + ko + gc + 4096, &lds[buf][1][(w << 4) + 64][0]);        \
  } while (0)

  QKSTAGE(0, 0);
  f32x4 pa = *(const f32x4*)(arow);
  f32x4 pb = *(const f32x4*)(arow + 4);
  __syncthreads();

  for (int kk = 0; kk < 24; ++kk) {
    const int buf = kk & 1;
    if (kk < 23) QKSTAGE(buf ^ 1, kk + 1);
    f32x4 na = fzero, nb = fzero;
    if (kk < 23) {
      na = *(const f32x4*)(arow + (kk + 1) * 32);
      nb = *(const f32x4*)(arow + (kk + 1) * 32 + 4);
    }
    bf16x8 ah, al; split8v(pa, pb, ah, al);
#pragma unroll
    for (int nt = 0; nt < 8; ++nt) {
      int br = nt * 16 + lr;
      int bo = (lh ^ ((br >> 1) & 3)) << 4;
      bf16x8 wh = *(const bf16x8*)&lds[buf][0][br][bo];
      bf16x8 wl = *(const bf16x8*)&lds[buf][1][br][bo];
      acc[nt] = __builtin_amdgcn_mfma_f32_16x16x32_bf16(ah, wh, acc[nt], 0, 0, 0);
      acc[nt] = __builtin_amdgcn_mfma_f32_16x16x32_bf16(ah, wl, acc[nt], 0, 0, 0);
      acc[nt] = __builtin_amdgcn_mfma_f32_16x16x32_bf16(al, wh, acc[nt], 0, 0, 0);
    }
    __syncthreads();
    pa = na; pb = nb;
  }
#undef QKSTAGE

#pragma unroll
  for (int nt = 0; nt < 8; ++nt) {
    int n = n0 + nt * 16 + lr;
    if (n >= DKP) continue;
    float bv = (n < DKV) ? bias[n] : 0.f;
#pragma unroll
    for (int r = 0; r < 4; ++r) {
      int m = m0 + w * 16 + lh * 4 + r;
      int bb = m >> 11, s = m & 2047;
      float val = (n < DKV) ? (acc[nt][r] + bv) : 0.f;
      ushort h = f2bf(val);
      size_t idx = ((size_t)(bb * 7 + (n >> 5)) * SS + s) * 32 + (n & 31);
      Ch[idx] = h;
      Cl[idx] = f2bf(val - bf2f(h));
    }
  }
}

// ---- V projection -> k-packed Vp[b][64][768][32] (unchanged R11) ----
__global__ __launch_bounds__(256, 3)
void gemm_v(const float* __restrict__ A, const ushort* __restrict__ Bw,
            const float* __restrict__ bias, ushort* __restrict__ Vp)
{
  const int m0 = blockIdx.x * 64;
  const int n0 = blockIdx.y * 256;
  const int tid = threadIdx.x;
  const int w  = tid >> 6;
  const int l  = tid & 63;
  const int lr = l & 15;
  const int lh = l >> 4;

  __shared__ __align__(16) char smem[36864];
  typedef char VBuf[256][64];
  VBuf* stage = (VBuf*)smem;
  ushort (*lt)[72] = (ushort(*)[72])smem;

  const int srow = (w << 4) + (l >> 2);
  const size_t gc = (size_t)srow * 64 + (size_t)((((l & 3) ^ ((srow >> 1) & 3))) << 4);
  const char* gvw = (const char*)Bw + (size_t)n0 * 64;

  const f32x4 fzero = {0.f, 0.f, 0.f, 0.f};
  f32x4 acc[16];
#pragma unroll
  for (int nt = 0; nt < 16; ++nt) acc[nt] = fzero;

  const float* arow = A + (size_t)(m0 + w * 16 + lr) * DD + lh * 8;

#define VSTAGE(buf, kk) do {                                              \
    size_t ko = (size_t)(kk) * (DD * 64);                                 \
    gload16(gvw + ko + gc,         &stage[buf][w << 4][0]);               \
    gload16(gvw + ko + gc + 4096,  &stage[buf][(w << 4) + 64][0]);        \
    gload16(gvw + ko + gc + 8192,  &stage[buf][(w << 4) + 128][0]);       \
    gload16(gvw + ko + gc + 12288, &stage[buf][(w << 4) + 192][0]);       \
  } while (0)

  VSTAGE(0, 0);
  f32x4 pa = *(const f32x4*)(arow);
  f32x4 pb = *(const f32x4*)(arow + 4);
  __syncthreads();

  for (int kk = 0; kk < 24; ++kk) {
    const int buf = kk & 1;
    if (kk < 23) VSTAGE(buf ^ 1, kk + 1);
    f32x4 na = fzero, nb = fzero;
    if (kk < 23) {
      na = *(const f32x4*)(arow + (kk + 1) * 32);
      nb = *(const f32x4*)(arow + (kk + 1) * 32 + 4);
    }
    bf16x8 af = cvt8v(pa, pb);
#pragma unroll
    for (int nt = 0; nt < 16; ++nt) {
      int br = nt * 16 + lr;
      int bo = (lh ^ ((br >> 1) & 3)) << 4;
      bf16x8 bfr = *(const bf16x8*)&stage[buf][br][bo];
      acc[nt] = __builtin_amdgcn_mfma_f32_16x16x32_bf16(af, bfr, acc[nt], 0, 0, 0);
    }
    __syncthreads();
    pa = na; pb = nb;
  }
#undef VSTAGE

#pragma unroll
  for (int nt = 0; nt < 16; ++nt) {
    int nl = nt * 16 + lr;
    float bv = bias[n0 + nl];
#pragma unroll
    for (int r = 0; r < 4; ++r)
      lt[nl][w * 16 + lh * 4 + r] = f2bf(acc[nt][r] + bv);
  }
  __syncthreads();
  const int bb = m0 >> 11;
  const int s0 = m0 & 2047;
  for (int i = tid; i < 256 * 64; i += 256) {
    int nn = i >> 6, mm = i & 63;
    int d = n0 + nn, t = s0 + mm;
    Vp[((size_t)(bb * 64 + (t >> 5)) * DD + d) * 32 + (t & 31)] = lt[nn][mm];
  }
}

// ---- pass 1: S = QK^T (split-bf16). Tile 128m x 256n, 8 waves of 64x64.
// Epilogue streams compressed: rcp(isc) f16 (L3-resident) + dmask bits (L2).
__global__ __launch_bounds__(512, 4)
void gemm_s(const ushort* __restrict__ Qph, const ushort* __restrict__ Qpl,
            const ushort* __restrict__ Kph, const ushort* __restrict__ Kpl,
            const ushort* __restrict__ riscp, const u64* __restrict__ dbits,
            ushort* __restrict__ Pp, float* __restrict__ Z)
{
  const int bid = blockIdx.x;
  const int bb = bid & 7;
  const int tt = bid >> 3;
  const int m0 = (tt & 15) * 128;
  const int n0 = (tt >> 4) * 256;
  const int tid = threadIdx.x;
  const int w  = tid >> 6;
  const int l  = tid & 63;
  const int lr = l & 15;
  const int lh = l >> 4;
  const int wm = w & 1;
  const int wn = w >> 1;

  __shared__ __align__(16) char Qhb[128][64];
  __shared__ __align__(16) char Qlb[128][64];
  __shared__ __align__(16) char Khb[256][64];
  __shared__ __align__(16) char Klb[256][64];

  const int srow = (w << 4) + (l >> 2);
  const size_t gc = (size_t)srow * 64 + (size_t)((((l & 3) ^ ((srow >> 1) & 3))) << 4);

  const char* gqh = (const char*)Qph + ((size_t)(bb * 7) * SS + m0) * 64;
  const char* gql = (const char*)Qpl + ((size_t)(bb * 7) * SS + m0) * 64;
  const char* gkh = (const char*)Kph + ((size_t)(bb * 7) * SS + n0) * 64;
  const char* gkl = (const char*)Kpl + ((size_t)(bb * 7) * SS + n0) * 64;

  const f32x4 fzero = {0.f, 0.f, 0.f, 0.f};
  f32x4 acc[4][4];
#pragma unroll
  for (int mf = 0; mf < 4; ++mf)
#pragma unroll
    for (int nf = 0; nf < 4; ++nf) acc[mf][nf] = fzero;

#define SSTAGE(kk) do {                                                 \
    size_t ko = (size_t)(kk) * (SS * 64);                               \
    gload16(gqh + ko + gc,        &Qhb[w << 4][0]);                     \
    gload16(gql + ko + gc,        &Qlb[w << 4][0]);                     \
    gload16(gkh + ko + gc,        &Khb[w << 4][0]);                     \
    gload16(gkh + ko + gc + 8192, &Khb[(w << 4) + 128][0]);             \
    gload16(gkl + ko + gc,        &Klb[w << 4][0]);                     \
    gload16(gkl + ko + gc + 8192, &Klb[(w << 4) + 128][0]);             \
  } while (0)

  SSTAGE(0);
  __syncthreads();
#pragma unroll 1
  for (int t = 0; t < 7; ++t) {
    bf16x8 bh[4], bl[4];
#pragma unroll
    for (int nf = 0; nf < 4; ++nf) {
      int br = wn * 64 + nf * 16 + lr;
      int bo = (lh ^ ((br >> 1) & 3)) << 4;
      bh[nf] = *(const bf16x8*)&Khb[br][bo];
      bl[nf] = *(const bf16x8*)&Klb[br][bo];
    }
#pragma unroll
    for (int mf = 0; mf < 4; ++mf) {
      int ar = wm * 64 + mf * 16 + lr;
      int ao = (lh ^ ((ar >> 1) & 3)) << 4;
      bf16x8 ah = *(const bf16x8*)&Qhb[ar][ao];
      bf16x8 al = *(const bf16x8*)&Qlb[ar][ao];
#pragma unroll
      for (int nf = 0; nf < 4; ++nf) {
        acc[mf][nf] = __builtin_amdgcn_mfma_f32_16x16x32_bf16(ah, bh[nf], acc[mf][nf], 0, 0, 0);
        acc[mf][nf] = __builtin_amdgcn_mfma_f32_16x16x32_bf16(ah, bl[nf], acc[mf][nf], 0, 0, 0);
        acc[mf][nf] = __builtin_amdgcn_mfma_f32_16x16x32_bf16(al, bh[nf], acc[mf][nf], 0, 0, 0);
      }
    }
    __syncthreads();
    if (t < 6) {
      SSTAGE(t + 1);
      __syncthreads();
    }
  }
#undef SSTAGE

  // epilogue: sval = acc * rcp_isc(f16), exp(.-MSHIFT), P~ = bit ? e/0.9 : 0
  const float KEEPR = 1.0f / 0.9f;
#pragma unroll
  for (int mf = 0; mf < 4; ++mf) {
#pragma unroll
    for (int r = 0; r < 4; ++r) {
      const int sr = m0 + wm * 64 + mf * 16 + lh * 4 + r;
      const u64 wbits = dbits[((size_t)bb * SS + sr) * (SS / 64) + (n0 >> 6) + wn];
      float z = 0.f;
#pragma unroll
      for (int nf = 0; nf < 4; ++nf) {
        const int tc = n0 + wn * 64 + nf * 16 + lr;
        union { _Float16 h; ushort u; } cv;
        cv.u = riscp[(size_t)sr * SS + tc];
        float sval = acc[mf][nf][r] * (float)cv.h;
        float e = __expf(sval - MSHIFT);
        z += e;
        float pm = ((wbits >> (nf * 16 + lr)) & 1ull) ? (e * KEEPR) : 0.f;
        Pp[((size_t)(bb * 64 + (tc >> 5)) * SS + sr) * 32 + (tc & 31)] = f2bf(pm);
      }
#pragma unroll
      for (int off = 1; off < 16; off <<= 1) z += __shfl_xor(z, off);
      if (lr == 0) atomicAdd(&Z[bb * SS + sr], z);
    }
  }
}

// ---- pass 2: O = (P~ V) / Z. Tile 128x128, 4 waves of 64x64 (unchanged R12) ----
__global__ __launch_bounds__(256, 4)
void gemm_pv(const ushort* __restrict__ Pp, const ushort* __restrict__ Vp,
             const float* __restrict__ Z, float* __restrict__ out)
{
  const int bid = blockIdx.x;
  const int bb = bid & 7;
  const int tt = bid >> 3;
  const int m0 = (tt & 15) * 128;
  const int n0 = (tt >> 4) * 128;
  const int tid = threadIdx.x;
  const int w  = tid >> 6;
  const int l  = tid & 63;
  const int lr = l & 15;
  const int lh = l >> 4;
  const int wm = w & 1;
  const int wn = w >> 1;

  __shared__ __align__(16) char Plb[2][128][64];
  __shared__ __align__(16) char Vlb[2][128][64];

  const int srow = (w << 4) + (l >> 2);
  const size_t gc = (size_t)srow * 64 + (size_t)((((l & 3) ^ ((srow >> 1) & 3))) << 4);

  const char* gpb = (const char*)Pp + ((size_t)(bb * 64) * SS + m0) * 64;
  const char* gvb = (const char*)Vp + ((size_t)(bb * 64) * DD + n0) * 64;

  const f32x4 fzero = {0.f, 0.f, 0.f, 0.f};
  f32x4 acc[4][4];
#pragma unroll
  for (int mf = 0; mf < 4; ++mf)
#pragma unroll
    for (int nf = 0; nf < 4; ++nf) acc[mf][nf] = fzero;

#define PVSTAGE(t) do {                                                   \
    size_t k0 = (size_t)(t) * 2;                                          \
    gload16(gpb + k0 * (SS * 64) + gc,              &Plb[0][w << 4][0]);  \
    gload16(gpb + k0 * (SS * 64) + gc + 4096,       &Plb[0][(w << 4) + 64][0]); \
    gload16(gpb + (k0 + 1) * (SS * 64) + gc,        &Plb[1][w << 4][0]);  \
    gload16(gpb + (k0 + 1) * (SS * 64) + gc + 4096, &Plb[1][(w << 4) + 64][0]); \
    gload16(gvb + k0 * (DD * 64) + gc,              &Vlb[0][w << 4][0]);  \
    gload16(gvb + k0 * (DD * 64) + gc + 4096,       &Vlb[0][(w << 4) + 64][0]); \
    gload16(gvb + (k0 + 1) * (DD * 64) + gc,        &Vlb[1][w << 4][0]);  \
    gload16(gvb + (k0 + 1) * (DD * 64) + gc + 4096, &Vlb[1][(w << 4) + 64][0]); \
  } while (0)

  PVSTAGE(0);
  __syncthreads();
#pragma unroll 1
  for (int t = 0; t < 32; ++t) {
#pragma unroll
    for (int pk = 0; pk < 2; ++pk) {
      bf16x8 bfr[4];
#pragma unroll
      for (int nf = 0; nf < 4; ++nf) {
        int br = wn * 64 + nf * 16 + lr;
        int bo = (lh ^ ((br >> 1) & 3)) << 4;
        bfr[nf] = *(const bf16x8*)&Vlb[pk][br][bo];
      }
#pragma unroll
      for (int mf = 0; mf < 4; ++mf) {
        int ar = wm * 64 + mf * 16 + lr;
        int ao = (lh ^ ((ar >> 1) & 3)) << 4;
        bf16x8 af = *(const bf16x8*)&Plb[pk][ar][ao];
#pragma unroll
        for (int nf = 0; nf < 4; ++nf)
          acc[mf][nf] = __builtin_amdgcn_mfma_f32_16x16x32_bf16(af, bfr[nf], acc[mf][nf], 0, 0, 0);
      }
    }
    __syncthreads();
    if (t < 31) {
      PVSTAGE(t + 1);
      __syncthreads();
    }
  }
#undef PVSTAGE

#pragma unroll
  for (int mf = 0; mf < 4; ++mf) {
#pragma unroll
    for (int r = 0; r < 4; ++r) {
      const int sr = m0 + wm * 64 + mf * 16 + lh * 4 + r;
      float rz = __builtin_amdgcn_rcpf(Z[bb * SS + sr]);
#pragma unroll
      for (int nf = 0; nf < 4; ++nf) {
        const int dc = n0 + wn * 64 + nf * 16 + lr;
        out[((size_t)bb * SS + sr) * DD + dc] = acc[mf][nf][r] * rz;
      }
    }
  }
}

extern "C" void kernel_launch(void* const* d_in, const int* in_sizes, int n_in,
                              void* d_out, int out_size, void* d_ws, size_t ws_size,
                              hipStream_t stream) {
  const float* x1  = (const float*)d_in[0];
  const float* x2  = (const float*)d_in[1];
  const float* x3  = (const float*)d_in[2];
  const float* Wq  = (const float*)d_in[3];
  const float* bq  = (const float*)d_in[4];
  const float* Wk  = (const float*)d_in[5];
  const float* bk  = (const float*)d_in[6];
  const float* Wv  = (const float*)d_in[7];
  const float* bv  = (const float*)d_in[8];
  const float* isc = (const float*)d_in[9];
  const float* dmk = (const float*)d_in[10];
  float* out = (float*)d_out;

  const size_t QKN = (size_t)NB * 7 * SS * 32;
  const size_t VPN = (size_t)NB * 64 * DD * 32;
  const size_t WN  = (size_t)WROWS * DD;
  const size_t NV  = (size_t)DD * DD;
  const size_t PPN = (size_t)NB * 64 * SS * 32;

  ushort* Qph = (ushort*)d_ws;
  ushort* Qpl = Qph + QKN;
  ushort* Kph = Qpl + QKN;
  ushort* Kpl = Kph + QKN;
  ushort* Vp  = Kpl + QKN;
  ushort* Wqh = Vp + VPN;
  ushort* Wql = Wqh + WN;
  ushort* Wkh = Wql + WN;
  ushort* Wkl = Wkh + WN;
  ushort* Wvb = Wkl + WN;
  ushort* Pp  = Wvb + NV;
  float*  Zb  = (float*)(Pp + PPN);                     // [8][2048]
  ushort* riscp = (ushort*)(Zb + NB * SS);              // [2048][2048] f16
  u64*    dbits = (u64*)(riscp + (size_t)SS * SS);      // [8][2048][32] u64

  dim3 blk(256);
  prep_w<<<dim3(512),  blk, 0, stream>>>(Wq, Wk, Wv, Wqh, Wql, Wkh, Wkl, Wvb);
  prep_sm<<<dim3(2048), blk, 0, stream>>>(isc, dmk, riscp, dbits, Zb);
  gemm_qk<<<dim3(256, 4), blk, 0, stream>>>(x1, x2, Wqh, Wql, Wkh, Wkl, bq, bk,
                                            Qph, Qpl, Kph, Kpl);
  gemm_v <<<dim3(256, 3), blk, 0, stream>>>(x3, Wvb, bv, Vp);
  gemm_s <<<dim3(1024), dim3(512), 0, stream>>>(Qph, Qpl, Kph, Kpl, riscp, dbits, Pp, Zb);
  gemm_pv<<<dim3(768),  dim3(256), 0, stream>>>(Pp, Vp, Zb, out);
}

// Round 14
// 263.115 us; speedup vs baseline: 1.0875x; 1.0875x over previous
//
#include <hip/hip_runtime.h>
#include <hip/hip_bf16.h>

typedef unsigned short ushort;
typedef unsigned long long u64;
typedef short bf16x8 __attribute__((ext_vector_type(8)));
typedef _Float16 f16x8 __attribute__((ext_vector_type(8)));
typedef float f32x4 __attribute__((ext_vector_type(4)));

#define NB 8
#define SS 2048
#define DD 768
#define DKV 214
#define DKP 224
#define WROWS 256
#define MSHIFT 40.0f

__device__ __forceinline__ float bf2f(ushort u) {
  union { unsigned int i; float f; } v; v.i = ((unsigned int)u) << 16; return v.f;
}
__device__ __forceinline__ ushort f2bf(float f) {
  union { float f; unsigned int i; } v; v.f = f;
  unsigned int x = v.i;
  return (ushort)((x + 0x7fffu + ((x >> 16) & 1u)) >> 16);
}
__device__ __forceinline__ ushort f2h(float f) {
  union { _Float16 h; ushort u; } cv; cv.h = (_Float16)f; return cv.u;
}
__device__ __forceinline__ bf16x8 cvt8v(f32x4 a, f32x4 b) {
  bf16x8 r;
#pragma unroll
  for (int j = 0; j < 4; ++j) { r[j] = (short)f2bf(a[j]); r[j + 4] = (short)f2bf(b[j]); }
  return r;
}
__device__ __forceinline__ f16x8 cvt8h(f32x4 a, f32x4 b) {
  f16x8 r;
#pragma unroll
  for (int j = 0; j < 4; ++j) { r[j] = (_Float16)a[j]; r[j + 4] = (_Float16)b[j]; }
  return r;
}
// async global->LDS, 16B per lane; LDS dest is wave-uniform base + lane*16
__device__ __forceinline__ void gload16(const void* g, void* l) {
  __builtin_amdgcn_global_load_lds(
      (const __attribute__((address_space(1))) void*)g,
      (__attribute__((address_space(3))) void*)l, 16, 0, 0);
}

// ---- stream prep: Z zero + dmask -> 1 bit/elem (4.2 MB), vectorized ----
__global__ __launch_bounds__(256)
void prep_sm(const float* __restrict__ dmk, u64* __restrict__ dbits,
             float* __restrict__ Z)
{
  const int tid0 = blockIdx.x * 256 + threadIdx.x;
  const int stride = gridDim.x * 256;
  for (int i = tid0; i < NB * SS; i += stride) Z[i] = 0.f;
  const size_t nwords = (size_t)NB * SS * SS / 64;
  for (size_t wi = tid0; wi < nwords; wi += stride) {
    const f32x4* p = (const f32x4*)(dmk + wi * 64);
    u64 m = 0;
#pragma unroll
    for (int j = 0; j < 16; ++j) {
      f32x4 v = p[j];
#pragma unroll
      for (int q = 0; q < 4; ++q) m |= (v[q] > 0.5f) ? (1ull << (j * 4 + q)) : 0ull;
    }
    dbits[wi] = m;
  }
}

// ---- weight prep. Wq,Wk -> k-packed f16 [24][256][32]; Wv -> k-packed bf16 [24][768][32] ----
__global__ __launch_bounds__(256)
void prep_w(const float* __restrict__ Wq, const float* __restrict__ Wk,
            const float* __restrict__ Wv,
            ushort* __restrict__ Wqp, ushort* __restrict__ Wkp,
            ushort* __restrict__ Wvb)
{
  const int NW = WROWS * DD;
  const int NV = DD * DD;
  for (int i = blockIdx.x * 256 + threadIdx.x; i < 2 * NW + NV; i += gridDim.x * 256) {
    if (i < NW) {
      int r = i / DD, c = i % DD;
      float v = (r < DKV) ? Wq[i] : 0.f;
      Wqp[(c >> 5) * (WROWS * 32) + r * 32 + (c & 31)] = f2h(v);
    } else if (i < 2 * NW) {
      int j = i - NW;
      int r = j / DD, c = j % DD;
      float v = (r < DKV) ? Wk[j] : 0.f;
      Wkp[(c >> 5) * (WROWS * 32) + r * 32 + (c & 31)] = f2h(v);
    } else {
      int j = i - 2 * NW;
      int r = j / DD, c = j % DD;
      Wvb[(c >> 5) * (DD * 32) + r * 32 + (c & 31)] = f2bf(Wv[j]);
    }
  }
}

// ---- fused Q+K projection (f16, single MFMA) -> k-packed f16 [b][7][2048][32] ----
__global__ __launch_bounds__(256, 4)
void gemm_qk(const float* __restrict__ x1, const float* __restrict__ x2,
             const ushort* __restrict__ Wqp, const ushort* __restrict__ Wkp,
             const float* __restrict__ bq, const float* __restrict__ bk,
             ushort* __restrict__ Qp, ushort* __restrict__ Kp)
{
  const int m0 = blockIdx.x * 64;
  const int which = blockIdx.y >> 1;
  const int n0 = (blockIdx.y & 1) * 128;
  const int tid = threadIdx.x;
  const int w  = tid >> 6;
  const int l  = tid & 63;
  const int lr = l & 15;
  const int lh = l >> 4;

  const float*  A    = which ? x2 : x1;
  const ushort* Bw   = which ? Wkp : Wqp;
  const float*  bias = which ? bk : bq;
  ushort* Cp = which ? Kp : Qp;

  __shared__ __align__(16) char lds[2][128][64];      // 16 KB

  const int srow = (w << 4) + (l >> 2);
  const size_t gc = (size_t)srow * 64 + (size_t)((((l & 3) ^ ((srow >> 1) & 3))) << 4);
  const char* gb = (const char*)Bw + (size_t)n0 * 64;

  const f32x4 fzero = {0.f, 0.f, 0.f, 0.f};
  f32x4 acc[8];
#pragma unroll
  for (int nt = 0; nt < 8; ++nt) acc[nt] = fzero;

  const float* arow = A + (size_t)(m0 + w * 16 + lr) * DD + lh * 8;

#define QKSTAGE(buf, kk) do {                                             \
    size_t ko = (size_t)(kk) * (WROWS * 64);                              \
    gload16(gb + ko + gc,        &lds[buf][w << 4][0]);                   \
    gload16(gb + ko + gc + 4096, &lds[buf][(w << 4) + 64][0]);            \
  } while (0)

  QKSTAGE(0, 0);
  f32x4 pa = *(const f32x4*)(arow);
  f32x4 pb = *(const f32x4*)(arow + 4);
  __syncthreads();

  for (int kk = 0; kk < 24; ++kk) {
    const int buf = kk & 1;
    if (kk < 23) QKSTAGE(buf ^ 1, kk + 1);
    f32x4 na = fzero, nb = fzero;
    if (kk < 23) {
      na = *(const f32x4*)(arow + (kk + 1) * 32);
      nb = *(const f32x4*)(arow + (kk + 1) * 32 + 4);
    }
    f16x8 af = cvt8h(pa, pb);
#pragma unroll
    for (int nt = 0; nt < 8; ++nt) {
      int br = nt * 16 + lr;
      int bo = (lh ^ ((br >> 1) & 3)) << 4;
      f16x8 wf = *(const f16x8*)&lds[buf][br][bo];
      acc[nt] = __builtin_amdgcn_mfma_f32_16x16x32_f16(af, wf, acc[nt], 0, 0, 0);
    }
    __syncthreads();
    pa = na; pb = nb;
  }
#undef QKSTAGE

#pragma unroll
  for (int nt = 0; nt < 8; ++nt) {
    int n = n0 + nt * 16 + lr;
    if (n >= DKP) continue;
    float bv = (n < DKV) ? bias[n] : 0.f;
#pragma unroll
    for (int r = 0; r < 4; ++r) {
      int m = m0 + w * 16 + lh * 4 + r;
      int bb = m >> 11, s = m & 2047;
      float val = (n < DKV) ? (acc[nt][r] + bv) : 0.f;
      Cp[((size_t)(bb * 7 + (n >> 5)) * SS + s) * 32 + (n & 31)] = f2h(val);
    }
  }
}

// ---- V projection -> k-packed Vp[b][64][768][32] bf16 (unchanged R11) ----
__global__ __launch_bounds__(256, 3)
void gemm_v(const float* __restrict__ A, const ushort* __restrict__ Bw,
            const float* __restrict__ bias, ushort* __restrict__ Vp)
{
  const int m0 = blockIdx.x * 64;
  const int n0 = blockIdx.y * 256;
  const int tid = threadIdx.x;
  const int w  = tid >> 6;
  const int l  = tid & 63;
  const int lr = l & 15;
  const int lh = l >> 4;

  __shared__ __align__(16) char smem[36864];
  typedef char VBuf[256][64];
  VBuf* stage = (VBuf*)smem;
  ushort (*lt)[72] = (ushort(*)[72])smem;

  const int srow = (w << 4) + (l >> 2);
  const size_t gc = (size_t)srow * 64 + (size_t)((((l & 3) ^ ((srow >> 1) & 3))) << 4);
  const char* gvw = (const char*)Bw + (size_t)n0 * 64;

  const f32x4 fzero = {0.f, 0.f, 0.f, 0.f};
  f32x4 acc[16];
#pragma unroll
  for (int nt = 0; nt < 16; ++nt) acc[nt] = fzero;

  const float* arow = A + (size_t)(m0 + w * 16 + lr) * DD + lh * 8;

#define VSTAGE(buf, kk) do {                                              \
    size_t ko = (size_t)(kk) * (DD * 64);                                 \
    gload16(gvw + ko + gc,         &stage[buf][w << 4][0]);               \
    gload16(gvw + ko + gc + 4096,  &stage[buf][(w << 4) + 64][0]);        \
    gload16(gvw + ko + gc + 8192,  &stage[buf][(w << 4) + 128][0]);       \
    gload16(gvw + ko + gc + 12288, &stage[buf][(w << 4) + 192][0]);       \
  } while (0)

  VSTAGE(0, 0);
  f32x4 pa = *(const f32x4*)(arow);
  f32x4 pb = *(const f32x4*)(arow + 4);
  __syncthreads();

  for (int kk = 0; kk < 24; ++kk) {
    const int buf = kk & 1;
    if (kk < 23) VSTAGE(buf ^ 1, kk + 1);
    f32x4 na = fzero, nb = fzero;
    if (kk < 23) {
      na = *(const f32x4*)(arow + (kk + 1) * 32);
      nb = *(const f32x4*)(arow + (kk + 1) * 32 + 4);
    }
    bf16x8 af = cvt8v(pa, pb);
#pragma unroll
    for (int nt = 0; nt < 16; ++nt) {
      int br = nt * 16 + lr;
      int bo = (lh ^ ((br >> 1) & 3)) << 4;
      bf16x8 bfr = *(const bf16x8*)&stage[buf][br][bo];
      acc[nt] = __builtin_amdgcn_mfma_f32_16x16x32_bf16(af, bfr, acc[nt], 0, 0, 0);
    }
    __syncthreads();
    pa = na; pb = nb;
  }
#undef VSTAGE

#pragma unroll
  for (int nt = 0; nt < 16; ++nt) {
    int nl = nt * 16 + lr;
    float bv = bias[n0 + nl];
#pragma unroll
    for (int r = 0; r < 4; ++r)
      lt[nl][w * 16 + lh * 4 + r] = f2bf(acc[nt][r] + bv);
  }
  __syncthreads();
  const int bb = m0 >> 11;
  const int s0 = m0 & 2047;
  for (int i = tid; i < 256 * 64; i += 256) {
    int nn = i >> 6, mm = i & 63;
    int d = n0 + nn, t = s0 + mm;
    Vp[((size_t)(bb * 64 + (t >> 5)) * DD + d) * 32 + (t & 31)] = lt[nn][mm];
  }
}

// ---- pass 1: S = QK^T in f16 (single MFMA). Tile 128m x 256n, 8 waves of 64x64.
// Dbuf 48 KB LDS, 1 barrier/step. Epilogue: raw isc f32 + rcp, dmask bits, exp shift.
__global__ __launch_bounds__(512, 4)
void gemm_s(const ushort* __restrict__ Qp, const ushort* __restrict__ Kp,
            const float* __restrict__ isc, const u64* __restrict__ dbits,
            ushort* __restrict__ Pp, float* __restrict__ Z)
{
  const int bid = blockIdx.x;
  const int bb = bid & 7;
  const int tt = bid >> 3;
  const int m0 = (tt & 15) * 128;
  const int n0 = (tt >> 4) * 256;
  const int tid = threadIdx.x;
  const int w  = tid >> 6;
  const int l  = tid & 63;
  const int lr = l & 15;
  const int lh = l >> 4;
  const int wm = w & 1;
  const int wn = w >> 1;

  __shared__ __align__(16) char Qb[2][128][64];   // 16 KB
  __shared__ __align__(16) char Kb[2][256][64];   // 32 KB

  const int srow = (w << 4) + (l >> 2);
  const size_t gc = (size_t)srow * 64 + (size_t)((((l & 3) ^ ((srow >> 1) & 3))) << 4);

  const char* gq = (const char*)Qp + ((size_t)(bb * 7) * SS + m0) * 64;
  const char* gk = (const char*)Kp + ((size_t)(bb * 7) * SS + n0) * 64;

  const f32x4 fzero = {0.f, 0.f, 0.f, 0.f};
  f32x4 acc[4][4];
#pragma unroll
  for (int mf = 0; mf < 4; ++mf)
#pragma unroll
    for (int nf = 0; nf < 4; ++nf) acc[mf][nf] = fzero;

#define SSTAGE(buf, kk) do {                                            \
    size_t ko = (size_t)(kk) * (SS * 64);                               \
    gload16(gq + ko + gc,        &Qb[buf][w << 4][0]);                  \
    gload16(gk + ko + gc,        &Kb[buf][w << 4][0]);                  \
    gload16(gk + ko + gc + 8192, &Kb[buf][(w << 4) + 128][0]);          \
  } while (0)

  SSTAGE(0, 0);
  __syncthreads();
#pragma unroll 1
  for (int t = 0; t < 7; ++t) {
    const int buf = t & 1;
    if (t < 6) SSTAGE(buf ^ 1, t + 1);
    f16x8 bfr[4];
#pragma unroll
    for (int nf = 0; nf < 4; ++nf) {
      int br = wn * 64 + nf * 16 + lr;
      int bo = (lh ^ ((br >> 1) & 3)) << 4;
      bfr[nf] = *(const f16x8*)&Kb[buf][br][bo];
    }
#pragma unroll
    for (int mf = 0; mf < 4; ++mf) {
      int ar = wm * 64 + mf * 16 + lr;
      int ao = (lh ^ ((ar >> 1) & 3)) << 4;
      f16x8 af = *(const f16x8*)&Qb[buf][ar][ao];
#pragma unroll
      for (int nf = 0; nf < 4; ++nf)
        acc[mf][nf] = __builtin_amdgcn_mfma_f32_16x16x32_f16(af, bfr[nf], acc[mf][nf], 0, 0, 0);
    }
    __syncthreads();
  }
#undef SSTAGE

  // epilogue: sval = acc * rcp(isc), exp(.-MSHIFT), P~ = bit ? e/0.9 : 0
  const float KEEPR = 1.0f / 0.9f;
#pragma unroll
  for (int mf = 0; mf < 4; ++mf) {
#pragma unroll
    for (int r = 0; r < 4; ++r) {
      const int sr = m0 + wm * 64 + mf * 16 + lh * 4 + r;
      const u64 wbits = dbits[((size_t)bb * SS + sr) * (SS / 64) + (n0 >> 6) + wn];
      float z = 0.f;
#pragma unroll
      for (int nf = 0; nf < 4; ++nf) {
        const int tc = n0 + wn * 64 + nf * 16 + lr;
        float iv = isc[(size_t)sr * SS + tc];
        float sval = acc[mf][nf][r] * __builtin_amdgcn_rcpf(iv);
        float e = __expf(sval - MSHIFT);
        z += e;
        float pm = ((wbits >> (nf * 16 + lr)) & 1ull) ? (e * KEEPR) : 0.f;
        Pp[((size_t)(bb * 64 + (tc >> 5)) * SS + sr) * 32 + (tc & 31)] = f2bf(pm);
      }
#pragma unroll
      for (int off = 1; off < 16; off <<= 1) z += __shfl_xor(z, off);
      if (lr == 0) atomicAdd(&Z[bb * SS + sr], z);
    }
  }
}

// ---- pass 2: O = (P~ V) / Z. Tile 128x128, 4 waves of 64x64 (unchanged R12) ----
__global__ __launch_bounds__(256, 4)
void gemm_pv(const ushort* __restrict__ Pp, const ushort* __restrict__ Vp,
             const float* __restrict__ Z, float* __restrict__ out)
{
  const int bid = blockIdx.x;
  const int bb = bid & 7;
  const int tt = bid >> 3;
  const int m0 = (tt & 15) * 128;
  const int n0 = (tt >> 4) * 128;
  const int tid = threadIdx.x;
  const int w  = tid >> 6;
  const int l  = tid & 63;
  const int lr = l & 15;
  const int lh = l >> 4;
  const int wm = w & 1;
  const int wn = w >> 1;

  __shared__ __align__(16) char Plb[2][128][64];
  __shared__ __align__(16) char Vlb[2][128][64];

  const int srow = (w << 4) + (l >> 2);
  const size_t gc = (size_t)srow * 64 + (size_t)((((l & 3) ^ ((srow >> 1) & 3))) << 4);

  const char* gpb = (const char*)Pp + ((size_t)(bb * 64) * SS + m0) * 64;
  const char* gvb = (const char*)Vp + ((size_t)(bb * 64) * DD + n0) * 64;

  const f32x4 fzero = {0.f, 0.f, 0.f, 0.f};
  f32x4 acc[4][4];
#pragma unroll
  for (int mf = 0; mf < 4; ++mf)
#pragma unroll
    for (int nf = 0; nf < 4; ++nf) acc[mf][nf] = fzero;

#define PVSTAGE(t) do {                                                   \
    size_t k0 = (size_t)(t) * 2;                                          \
    gload16(gpb + k0 * (SS * 64) + gc,              &Plb[0][w << 4][0]);  \
    gload16(gpb + k0 * (SS * 64) + gc + 4096,       &Plb[0][(w << 4) + 64][0]); \
    gload16(gpb + (k0 + 1) * (SS * 64) + gc,        &Plb[1][w << 4][0]);  \
    gload16(gpb + (k0 + 1) * (SS * 64) + gc + 4096, &Plb[1][(w << 4) + 64][0]); \
    gload16(gvb + k0 * (DD * 64) + gc,              &Vlb[0][w << 4][0]);  \
    gload16(gvb + k0 * (DD * 64) + gc + 4096,       &Vlb[0][(w << 4) + 64][0]); \
    gload16(gvb + (k0 + 1) * (DD * 64) + gc,        &Vlb[1][w << 4][0]);  \
    gload16(gvb + (k0 + 1) * (DD * 64) + gc + 4096, &Vlb[1][(w << 4) + 64][0]); \
  } while (0)

  PVSTAGE(0);
  __syncthreads();
#pragma unroll 1
  for (int t = 0; t < 32; ++t) {
#pragma unroll
    for (int pk = 0; pk < 2; ++pk) {
      bf16x8 bfr[4];
#pragma unroll
      for (int nf = 0; nf < 4; ++nf) {
        int br = wn * 64 + nf * 16 + lr;
        int bo = (lh ^ ((br >> 1) & 3)) << 4;
        bfr[nf] = *(const bf16x8*)&Vlb[pk][br][bo];
      }
#pragma unroll
      for (int mf = 0; mf < 4; ++mf) {
        int ar = wm * 64 + mf * 16 + lr;
        int ao = (lh ^ ((ar >> 1) & 3)) << 4;
        bf16x8 af = *(const bf16x8*)&Plb[pk][ar][ao];
#pragma unroll
        for (int nf = 0; nf < 4; ++nf)
          acc[mf][nf] = __builtin_amdgcn_mfma_f32_16x16x32_bf16(af, bfr[nf], acc[mf][nf], 0, 0, 0);
      }
    }
    __syncthreads();
    if (t < 31) {
      PVSTAGE(t + 1);
      __syncthreads();
    }
  }
#undef PVSTAGE

#pragma unroll
  for (int mf = 0; mf < 4; ++mf) {
#pragma unroll
    for (int r = 0; r < 4; ++r) {
      const int sr = m0 + wm * 64 + mf * 16 + lh * 4 + r;
      float rz = __builtin_amdgcn_rcpf(Z[bb * SS + sr]);
#pragma unroll
      for (int nf = 0; nf < 4; ++nf) {
        const int dc = n0 + wn * 64 + nf * 16 + lr;
        out[((size_t)bb * SS + sr) * DD + dc] = acc[mf][nf][r] * rz;
      }
    }
  }
}

extern "C" void kernel_launch(void* const* d_in, const int* in_sizes, int n_in,
                              void* d_out, int out_size, void* d_ws, size_t ws_size,
                              hipStream_t stream) {
  const float* x1  = (const float*)d_in[0];
  const float* x2  = (const float*)d_in[1];
  const float* x3  = (const float*)d_in[2];
  const float* Wq  = (const float*)d_in[3];
  const float* bq  = (const float*)d_in[4];
  const float* Wk  = (const float*)d_in[5];
  const float* bk  = (const float*)d_in[6];
  const float* Wv  = (const float*)d_in[7];
  const float* bv  = (const float*)d_in[8];
  const float* isc = (const float*)d_in[9];
  const float* dmk = (const float*)d_in[10];
  float* out = (float*)d_out;

  const size_t QKN = (size_t)NB * 7 * SS * 32;        // 3.67M (f16)
  const size_t VPN = (size_t)NB * 64 * DD * 32;       // 12.6M (bf16)
  const size_t WN  = (size_t)WROWS * DD;
  const size_t NV  = (size_t)DD * DD;
  const size_t PPN = (size_t)NB * 64 * SS * 32;       // 33.5M (bf16)

  ushort* Qp  = (ushort*)d_ws;
  ushort* Kp  = Qp + QKN;
  ushort* Vp  = Kp + QKN;
  ushort* Wqp = Vp + VPN;
  ushort* Wkp = Wqp + WN;
  ushort* Wvb = Wkp + WN;
  ushort* Pp  = Wvb + NV;
  float*  Zb  = (float*)(Pp + PPN);                   // [8][2048]
  u64*    dbits = (u64*)(Zb + NB * SS);               // [8][2048][32] u64

  dim3 blk(256);
  prep_w<<<dim3(512),  blk, 0, stream>>>(Wq, Wk, Wv, Wqp, Wkp, Wvb);
  prep_sm<<<dim3(2048), blk, 0, stream>>>(dmk, dbits, Zb);
  gemm_qk<<<dim3(256, 4), blk, 0, stream>>>(x1, x2, Wqp, Wkp, bq, bk, Qp, Kp);
  gemm_v <<<dim3(256, 3), blk, 0, stream>>>(x3, Wvb, bv, Vp);
  gemm_s <<<dim3(1024), dim3(512), 0, stream>>>(Qp, Kp, isc, dbits, Pp, Zb);
  gemm_pv<<<dim3(768),  dim3(256), 0, stream>>>(Pp, Vp, Zb, out);
}